// Round 1
// baseline (73.187 us; speedup 1.0000x reference)
//
#include <hip/hip_runtime.h>
#include <math.h>

#define BB 4
#define TQ 256
#define TV 256
#define DD 512
#define UU 128
#define NEGV (-1e9f)

// ---------------- kernel 0: mask prep with dtype-layout detection ----------------
// mask is bool[B,TV] in the reference; the harness may hand it to us as
// uint8 (1B/elem), int32 (4B/elem), or float32 (4B/elem). Detect from the
// first 1024 bytes (safe to read in every layout since B*TV=1024 elements):
//   - any byte at (i%4)==3 equal to 0x3f  -> float32 (1.0f = 00 00 80 3f)
//   - else any nonzero byte at (i%4)!=0   -> uint8/bool layout
//   - else                                -> int32 layout (bytes 1..3 all zero)
// Emits maskV[b*TV+v] = +inf (valid) or -1e9 (masked); applied via fminf.
__global__ void mask_prep_kernel(const unsigned char* __restrict__ m,
                                 float* __restrict__ maskV) {
    __shared__ int floatFlag, byteFlag;
    int t = threadIdx.x;  // 1024 threads, one block
    if (t == 0) { floatFlag = 0; byteFlag = 0; }
    __syncthreads();
    unsigned char c = m[t];
    if ((t & 3) == 3 && c == 0x3f) floatFlag = 1;   // benign same-value race
    if ((t & 3) != 0 && c != 0)    byteFlag  = 1;
    __syncthreads();
    bool ok;
    if (floatFlag)      ok = (m[4 * t + 3] != 0);   // buffer proven 4B/elem
    else if (byteFlag)  ok = (c != 0);
    else                ok = (m[4 * t] != 0);       // int32 little-endian LSB
    maskV[t] = ok ? __builtin_inff() : NEGV;
}

// ---------------- kernel 1: q and k projections (k written transposed) ----------------
#define PROJ_ROWS 4
__global__ __launch_bounds__(128) void proj_kernel(
    const float* __restrict__ query, const float* __restrict__ value,
    const float* __restrict__ W1, const float* __restrict__ W2,
    float* __restrict__ qp /*[B*TQ][U]*/, float* __restrict__ kT /*[B][U][TV]*/) {
    const int nb = (BB * TQ) / PROJ_ROWS;         // 256 groups per projection
    int which = blockIdx.x / nb;                   // 0 = q-proj, 1 = k-proj
    int grp = blockIdx.x % nb;
    int row0 = grp * PROJ_ROWS;                    // never crosses a batch (TV%4==0)
    const float* X = which ? value : query;
    const float* W = which ? W2 : W1;

    __shared__ float xs[PROJ_ROWS * DD];           // 8 KB: 4 input rows
    int u = threadIdx.x;                           // 0..127, one output column
    const float4* src = (const float4*)(X + (size_t)row0 * DD);
    float4* dst = (float4*)xs;
    for (int i = u; i < PROJ_ROWS * DD / 4; i += 128) dst[i] = src[i];
    __syncthreads();

    float a0 = 0.f, a1 = 0.f, a2 = 0.f, a3 = 0.f;
    #pragma unroll 4
    for (int d = 0; d < DD; ++d) {
        float w = W[d * UU + u];                   // coalesced across u
        a0 = fmaf(xs[0 * DD + d], w, a0);          // LDS broadcast reads
        a1 = fmaf(xs[1 * DD + d], w, a1);
        a2 = fmaf(xs[2 * DD + d], w, a2);
        a3 = fmaf(xs[3 * DD + d], w, a3);
    }
    if (which == 0) {
        qp[(size_t)(row0 + 0) * UU + u] = a0;
        qp[(size_t)(row0 + 1) * UU + u] = a1;
        qp[(size_t)(row0 + 2) * UU + u] = a2;
        qp[(size_t)(row0 + 3) * UU + u] = a3;
    } else {
        int b = row0 / TV, v = row0 % TV;
        float* kb = kT + (size_t)b * UU * TV + (size_t)u * TV + v;
        kb[0] = a0; kb[1] = a1; kb[2] = a2; kb[3] = a3;
    }
}

// ---------------- kernel 2: additive scores + masked softmax -> weights ----------------
__global__ __launch_bounds__(256) void scores_kernel(
    const float* __restrict__ qp, const float* __restrict__ kT,
    const float* __restrict__ scale, const float* __restrict__ maskV,
    float* __restrict__ weights /* d_out + B*TQ*D */) {
    int bq = blockIdx.x;            // 0..1023 : (b, q-row)
    int b = bq >> 8;
    int v = threadIdx.x;            // 0..255 : one value position
    __shared__ float qs[UU], sc[UU];
    if (v < UU) { qs[v] = qp[(size_t)bq * UU + v]; sc[v] = scale[v]; }
    __syncthreads();

    const float* kb = kT + (size_t)b * UU * TV;
    float s = 0.f;
    #pragma unroll 4
    for (int uu = 0; uu < UU; ++uu) {
        float x = qs[uu] + kb[(size_t)uu * TV + v];   // coalesced across v
        // tanh(x) = 1 - 2/(1+exp(2x)); saturates correctly at +-inf
        float e = __expf(2.f * x);
        float th = 1.f - 2.f / (1.f + e);
        s = fmaf(sc[uu], th, s);
    }
    s = fminf(s, maskV[b * TV + v]);   // valid: min(s,+inf)=s ; masked: -1e9

    // masked softmax across the 256 threads (4 wave64)
    __shared__ float redM[4], redS[4];
    float m = s;
    #pragma unroll
    for (int off = 32; off >= 1; off >>= 1) m = fmaxf(m, __shfl_xor(m, off));
    if ((v & 63) == 0) redM[v >> 6] = m;
    __syncthreads();
    m = fmaxf(fmaxf(redM[0], redM[1]), fmaxf(redM[2], redM[3]));
    float e = __expf(s - m);
    float t = e;
    #pragma unroll
    for (int off = 32; off >= 1; off >>= 1) t += __shfl_xor(t, off);
    if ((v & 63) == 0) redS[v >> 6] = t;
    __syncthreads();
    float sum = (redS[0] + redS[1]) + (redS[2] + redS[3]);
    weights[(size_t)bq * TV + v] = e / sum;
}

// ---------------- kernel 3: context = weights @ value ----------------
#define CTX_ROWS 4
__global__ __launch_bounds__(512) void context_kernel(
    const float* __restrict__ weights, const float* __restrict__ value,
    float* __restrict__ ctx) {
    int grp = blockIdx.x;                       // 0..255
    int b = grp / (TQ / CTX_ROWS);
    int q0 = (grp % (TQ / CTX_ROWS)) * CTX_ROWS;
    __shared__ float w[CTX_ROWS * TV];          // 4 KB, rows are contiguous
    int tid = threadIdx.x;                      // 0..511 : one output column d
    {
        const float* wsrc = weights + (size_t)(b * TQ + q0) * TV;
        for (int i = tid; i < CTX_ROWS * TV; i += 512) w[i] = wsrc[i];
    }
    __syncthreads();
    const float* vb = value + (size_t)b * TV * DD;
    float a0 = 0.f, a1 = 0.f, a2 = 0.f, a3 = 0.f;
    #pragma unroll 4
    for (int t = 0; t < TV; ++t) {
        float vv = vb[(size_t)t * DD + tid];    // coalesced across d
        a0 = fmaf(w[0 * TV + t], vv, a0);       // LDS broadcast
        a1 = fmaf(w[1 * TV + t], vv, a1);
        a2 = fmaf(w[2 * TV + t], vv, a2);
        a3 = fmaf(w[3 * TV + t], vv, a3);
    }
    float* out = ctx + (size_t)(b * TQ + q0) * DD + tid;
    out[0 * DD] = a0; out[1 * DD] = a1; out[2 * DD] = a2; out[3 * DD] = a3;
}

extern "C" void kernel_launch(void* const* d_in, const int* in_sizes, int n_in,
                              void* d_out, int out_size, void* d_ws, size_t ws_size,
                              hipStream_t stream) {
    const float* query = (const float*)d_in[0];
    const float* value = (const float*)d_in[1];
    const unsigned char* mask = (const unsigned char*)d_in[2];
    const float* W1 = (const float*)d_in[3];
    const float* W2 = (const float*)d_in[4];
    const float* scale = (const float*)d_in[5];

    float* ctx = (float*)d_out;                          // [B,TQ,D]
    float* weights = (float*)d_out + (size_t)BB * TQ * DD; // [B,TQ,TV]

    float* qp = (float*)d_ws;                            // B*TQ*U floats
    float* kT = qp + (size_t)BB * TQ * UU;               // B*U*TV floats
    float* maskV = kT + (size_t)BB * UU * TV;            // B*TV floats
    // total ws use: ~1.03 MB

    mask_prep_kernel<<<1, BB * TV, 0, stream>>>(mask, maskV);
    proj_kernel<<<2 * (BB * TQ) / PROJ_ROWS, 128, 0, stream>>>(
        query, value, W1, W2, qp, kT);
    scores_kernel<<<BB * TQ, 256, 0, stream>>>(qp, kT, scale, maskV, weights);
    context_kernel<<<(BB * TQ) / CTX_ROWS, 512, 0, stream>>>(weights, value, ctx);
}

// Round 2
// 65.786 us; speedup vs baseline: 1.1125x; 1.1125x over previous
//
#include <hip/hip_runtime.h>
#include <math.h>

#define BB 4
#define TQ 256
#define TV 256
#define DD 512
#define UU 128
#define NEGV (-1e9f)

// ---------------- kernel 0: mask prep with dtype-layout detection ----------------
__global__ void mask_prep_kernel(const unsigned char* __restrict__ m,
                                 float* __restrict__ maskV) {
    __shared__ int floatFlag, byteFlag;
    int t = threadIdx.x;  // 1024 threads, one block
    if (t == 0) { floatFlag = 0; byteFlag = 0; }
    __syncthreads();
    unsigned char c = m[t];
    if ((t & 3) == 3 && c == 0x3f) floatFlag = 1;   // float32 1.0f tail byte
    if ((t & 3) != 0 && c != 0)    byteFlag  = 1;   // nonzero off-word byte -> u8
    __syncthreads();
    bool ok;
    if (floatFlag)      ok = (m[4 * t + 3] != 0);
    else if (byteFlag)  ok = (c != 0);
    else                ok = (m[4 * t] != 0);       // int32 LSB
    maskV[t] = ok ? __builtin_inff() : NEGV;
}

// ---------------- kernel 1: projections, split-K, 8 rows/block ----------------
// grid = 2 proj * 128 row-groups * 2 k-chunks = 512 blocks, 256 threads.
// Partials: partQ[kc][row][u] (in d_out weights region),
//           partK[kc][b][u][v] (transposed, in d_out ctx region).
#define PR_ROWS 8
#define PR_KC 2
#define PR_KLEN (DD / PR_KC)   // 256
__global__ __launch_bounds__(256) void proj_kernel(
    const float* __restrict__ query, const float* __restrict__ value,
    const float* __restrict__ W1, const float* __restrict__ W2,
    float* __restrict__ partQ, float* __restrict__ partK) {
    int bid = blockIdx.x;
    int kc    = bid & 1;
    int grp   = (bid >> 1) & 127;
    int which = bid >> 8;                 // 0 = q-proj, 1 = k-proj
    int row0 = grp * PR_ROWS;
    const float* X = which ? value : query;
    const float* W = which ? W2 : W1;

    __shared__ float xs[PR_ROWS * PR_KLEN];   // 8 KB
    int tid = threadIdx.x;
    {   // stage 8 rows x 256 d (k-chunk) as float4
        const float4* dummy;
        (void)dummy;
        for (int idx = tid; idx < PR_ROWS * PR_KLEN / 4; idx += 256) {
            int row = idx >> 6, off = idx & 63;   // 64 float4 per row
            const float4* src =
                (const float4*)(X + (size_t)(row0 + row) * DD + kc * PR_KLEN);
            ((float4*)xs)[idx] = src[off];
        }
    }
    __syncthreads();

    int g = tid >> 7;          // 0/1: which 4-row half
    int u = tid & 127;
    const float* Wp = W + (size_t)kc * PR_KLEN * UU + u;
    const float* x0 = xs + (size_t)(4 * g) * PR_KLEN;
    float a0 = 0.f, a1 = 0.f, a2 = 0.f, a3 = 0.f;
    #pragma unroll 8
    for (int d = 0; d < PR_KLEN; ++d) {
        float w = Wp[(size_t)d * UU];            // coalesced across u; L1/L2 hit
        a0 = fmaf(x0[d], w, a0);                  // LDS broadcast
        a1 = fmaf(x0[PR_KLEN + d], w, a1);
        a2 = fmaf(x0[2 * PR_KLEN + d], w, a2);
        a3 = fmaf(x0[3 * PR_KLEN + d], w, a3);
    }
    if (which == 0) {
        float* p = partQ + ((size_t)kc * (BB * TQ) + row0 + 4 * g) * UU + u;
        p[0 * UU] = a0; p[1 * UU] = a1; p[2 * UU] = a2; p[3 * UU] = a3;
    } else {
        int b = row0 >> 8;
        int v0 = (row0 & 255) + 4 * g;
        float* p = partK + (((size_t)kc * BB + b) * UU + u) * TV + v0;
        p[0] = a0; p[1] = a1; p[2] = a2; p[3] = a3;
    }
}

// ---------------- kernel 1b: sum the 2 k-chunks ----------------
__global__ __launch_bounds__(256) void proj_reduce_kernel(
    const float* __restrict__ partQ, const float* __restrict__ partK,
    float* __restrict__ qp, float* __restrict__ kT) {
    size_t t = (size_t)blockIdx.x * 256 + threadIdx.x;   // 0..131071
    const size_t CH = (size_t)BB * TQ * UU;              // 131072
    qp[t] = partQ[t] + partQ[t + CH];
    kT[t] = partK[t] + partK[t + CH];
}

// ---------------- kernel 2: scores + masked softmax, 4 q-rows/block ----------------
__global__ __launch_bounds__(256) void scores_kernel(
    const float* __restrict__ qp, const float* __restrict__ kT,
    const float* __restrict__ scale, const float* __restrict__ maskV,
    float* __restrict__ weights) {
    int blk = blockIdx.x;               // 0..255
    int b = blk >> 6;
    int q0 = (blk & 63) * 4;
    int v = threadIdx.x;                // 0..255
    __shared__ float qs[4 * UU], sc[UU];
    if (v < UU) sc[v] = scale[v];
    for (int i = v; i < 4 * UU; i += 256)
        qs[i] = qp[((size_t)(b * TQ + q0) + (i >> 7)) * UU + (i & 127)];
    __syncthreads();

    const float* kb = kT + (size_t)b * UU * TV + v;
    float s0 = 0.f, s1 = 0.f, s2 = 0.f, s3 = 0.f;
    #pragma unroll 4
    for (int u = 0; u < UU; ++u) {
        float kv = kb[(size_t)u * TV];            // coalesced across v
        float w = sc[u];
        float x0 = qs[u] + kv;
        float x1 = qs[UU + u] + kv;
        float x2 = qs[2 * UU + u] + kv;
        float x3 = qs[3 * UU + u] + kv;
        // tanh(x) = 1 - 2/(1+exp(2x))
        s0 = fmaf(w, 1.f - 2.f / (1.f + __expf(2.f * x0)), s0);
        s1 = fmaf(w, 1.f - 2.f / (1.f + __expf(2.f * x1)), s1);
        s2 = fmaf(w, 1.f - 2.f / (1.f + __expf(2.f * x2)), s2);
        s3 = fmaf(w, 1.f - 2.f / (1.f + __expf(2.f * x3)), s3);
    }
    float mk = maskV[b * TV + v];
    float s[4] = { fminf(s0, mk), fminf(s1, mk), fminf(s2, mk), fminf(s3, mk) };

    __shared__ float redM[4][4], redS[4][4];
    int wid = v >> 6, lane = v & 63;
    float m[4], e[4];
    #pragma unroll
    for (int r = 0; r < 4; ++r) {
        float mm = s[r];
        #pragma unroll
        for (int off = 32; off >= 1; off >>= 1) mm = fmaxf(mm, __shfl_xor(mm, off));
        if (lane == 0) redM[r][wid] = mm;
    }
    __syncthreads();
    #pragma unroll
    for (int r = 0; r < 4; ++r) {
        m[r] = fmaxf(fmaxf(redM[r][0], redM[r][1]), fmaxf(redM[r][2], redM[r][3]));
        e[r] = __expf(s[r] - m[r]);
        float t = e[r];
        #pragma unroll
        for (int off = 32; off >= 1; off >>= 1) t += __shfl_xor(t, off);
        if (lane == 0) redS[r][wid] = t;
    }
    __syncthreads();
    #pragma unroll
    for (int r = 0; r < 4; ++r) {
        float sum = (redS[r][0] + redS[r][1]) + (redS[r][2] + redS[r][3]);
        weights[(size_t)(b * TQ + q0 + r) * TV + v] = e[r] / sum;
    }
}

// ---------------- kernel 3: context = weights @ value, 8 rows x 256-col split ----------------
__global__ __launch_bounds__(256) void context_kernel(
    const float* __restrict__ weights, const float* __restrict__ value,
    float* __restrict__ ctx) {
    int bid = blockIdx.x;               // 0..255
    int dhalf = bid & 1;
    int grp = bid >> 1;                 // 0..127
    int b = grp >> 5;
    int q0 = (grp & 31) * 8;
    int tid = threadIdx.x;              // 0..255 : column within half
    __shared__ float w[8 * TV];         // 8 KB
    {
        const float* wsrc = weights + (size_t)(b * TQ + q0) * TV;
        for (int i = tid; i < 8 * TV; i += 256) w[i] = wsrc[i];
    }
    __syncthreads();
    const float* vb = value + (size_t)b * TV * DD + dhalf * 256 + tid;
    float a0=0.f,a1=0.f,a2=0.f,a3=0.f,a4=0.f,a5=0.f,a6=0.f,a7=0.f;
    #pragma unroll 4
    for (int t = 0; t < TV; ++t) {
        float vv = vb[(size_t)t * DD];            // coalesced
        a0 = fmaf(w[0 * TV + t], vv, a0);
        a1 = fmaf(w[1 * TV + t], vv, a1);
        a2 = fmaf(w[2 * TV + t], vv, a2);
        a3 = fmaf(w[3 * TV + t], vv, a3);
        a4 = fmaf(w[4 * TV + t], vv, a4);
        a5 = fmaf(w[5 * TV + t], vv, a5);
        a6 = fmaf(w[6 * TV + t], vv, a6);
        a7 = fmaf(w[7 * TV + t], vv, a7);
    }
    float* out = ctx + (size_t)(b * TQ + q0) * DD + dhalf * 256 + tid;
    out[0*DD]=a0; out[1*DD]=a1; out[2*DD]=a2; out[3*DD]=a3;
    out[4*DD]=a4; out[5*DD]=a5; out[6*DD]=a6; out[7*DD]=a7;
}

extern "C" void kernel_launch(void* const* d_in, const int* in_sizes, int n_in,
                              void* d_out, int out_size, void* d_ws, size_t ws_size,
                              hipStream_t stream) {
    const float* query = (const float*)d_in[0];
    const float* value = (const float*)d_in[1];
    const unsigned char* mask = (const unsigned char*)d_in[2];
    const float* W1 = (const float*)d_in[3];
    const float* W2 = (const float*)d_in[4];
    const float* scale = (const float*)d_in[5];

    float* ctx = (float*)d_out;                              // [B,TQ,D]  (2 MB)
    float* weights = (float*)d_out + (size_t)BB * TQ * DD;   // [B,TQ,TV] (1 MB)

    // scratch: qp/kT/maskV in ws (1.03 MB, same budget as round 0).
    float* qp = (float*)d_ws;                                // 512 KB
    float* kT = qp + (size_t)BB * TQ * UU;                   // 512 KB
    float* maskV = kT + (size_t)BB * UU * TV;                // 4 KB
    // partials reuse d_out: partQ (1 MB) in weights region (consumed by
    // reduce before scores writes weights); partK (1 MB) in ctx region
    // (consumed by reduce; ctx written last by context_kernel).
    float* partQ = weights;
    float* partK = ctx;

    mask_prep_kernel<<<1, BB * TV, 0, stream>>>(mask, maskV);
    proj_kernel<<<512, 256, 0, stream>>>(query, value, W1, W2, partQ, partK);
    proj_reduce_kernel<<<512, 256, 0, stream>>>(partQ, partK, qp, kT);
    scores_kernel<<<BB * TQ / 4, 256, 0, stream>>>(qp, kT, scale, maskV, weights);
    context_kernel<<<(BB * TQ / 8) * 2, 256, 0, stream>>>(weights, value, ctx);
}

// Round 3
// 50.228 us; speedup vs baseline: 1.4571x; 1.3098x over previous
//
#include <hip/hip_runtime.h>
#include <math.h>

#define BB 4
#define TQ 256
#define TV 256
#define DD 512
#define UU 128
#define NEGV (-1e9f)

__device__ __forceinline__ float fast_rcp(float x) {
    return __builtin_amdgcn_rcpf(x);   // v_rcp_f32, ~1ulp*few, plenty for 9.7e-3
}

// ---------------- kernel 1: q & k projections, split-K inside block ----------------
// grid 512 x 256 thr. blocks 0..255: q-proj (4 rows each); 256..511: k-proj.
// threads = 128 u-cols x 2 K-halves; halves combined through LDS.
__global__ __launch_bounds__(256) void proj_kernel(
    const float* __restrict__ query, const float* __restrict__ value,
    const float* __restrict__ W1, const float* __restrict__ W2,
    float* __restrict__ qp /*[B*TQ][U]*/, float* __restrict__ kT /*[B][U][TV]*/) {
    int bid = blockIdx.x;
    int which = bid >> 8;              // 0 = q, 1 = k
    int row0 = (bid & 255) * 4;
    const float* X = which ? value : query;
    const float* W = which ? W2 : W1;

    __shared__ float xs[4 * DD];       // 8 KB: 4 input rows
    __shared__ float cmb[4][UU];       // 2 KB: split-K partials
    int tid = threadIdx.x;
    for (int i = tid; i < 4 * DD / 4; i += 256)
        ((float4*)xs)[i] = ((const float4*)(X + (size_t)row0 * DD))[i];
    __syncthreads();

    int kc = tid >> 7;                 // K-half
    int u = tid & 127;
    const float* Wp = W + (size_t)(kc * (DD / 2)) * UU + u;
    const float* x0 = xs + kc * (DD / 2);
    float a0 = 0.f, a1 = 0.f, a2 = 0.f, a3 = 0.f;
    #pragma unroll 8
    for (int d = 0; d < DD / 2; ++d) {
        float w = Wp[(size_t)d * UU];          // coalesced across u, 8 in flight
        a0 = fmaf(x0[d], w, a0);               // LDS broadcast (b128-merged)
        a1 = fmaf(x0[DD + d], w, a1);
        a2 = fmaf(x0[2 * DD + d], w, a2);
        a3 = fmaf(x0[3 * DD + d], w, a3);
    }
    if (kc) { cmb[0][u] = a0; cmb[1][u] = a1; cmb[2][u] = a2; cmb[3][u] = a3; }
    __syncthreads();
    if (!kc) {
        a0 += cmb[0][u]; a1 += cmb[1][u]; a2 += cmb[2][u]; a3 += cmb[3][u];
        if (which == 0) {
            float* p = qp + (size_t)row0 * UU + u;
            p[0 * UU] = a0; p[1 * UU] = a1; p[2 * UU] = a2; p[3 * UU] = a3;
        } else {
            int b = row0 >> 8, v0 = row0 & 255;
            float* p = kT + ((size_t)b * UU + u) * TV + v0;
            p[0] = a0; p[1] = a1; p[2] = a2; p[3] = a3;
        }
    }
}

// ---------------- kernel 2: scores + masked softmax + context, fused ----------------
// grid 256 x 256 thr; each block owns 4 q-rows of one batch.
__global__ __launch_bounds__(256) void attn_kernel(
    const float* __restrict__ qp, const float* __restrict__ kT,
    const float* __restrict__ scale, const unsigned char* __restrict__ m,
    const float* __restrict__ value,
    float* __restrict__ ctx, float* __restrict__ weights) {
    int blk = blockIdx.x;
    int b = blk >> 6;
    int q0 = (blk & 63) * 4;
    int v = threadIdx.x;               // 0..255 : one value position

    __shared__ float qs[4 * UU];       // 2 KB
    __shared__ float sc[UU];
    __shared__ float wls[4 * TV];      // 4 KB: weights for context phase
    __shared__ int flagF, flagB;
    __shared__ float redM[4][4], redS[4][4];

    if (v == 0) { flagF = 0; flagB = 0; }
    if (v < UU) sc[v] = scale[v];
    for (int i = v; i < 4 * UU; i += 256)
        qs[i] = qp[(size_t)(b * TQ + q0) * UU + i];   // rows contiguous
    __syncthreads();

    // ---- mask layout detection from the always-safe first 1024 bytes ----
    {
        uchar4 c4 = ((const uchar4*)m)[v];           // bytes 4v..4v+3
        if (c4.w == 0x3f) flagF = 1;                 // float32 1.0f tail byte
        if (c4.y | c4.z | c4.w) flagB = 1;           // nonzero off-word -> u8
    }
    __syncthreads();
    float mk;
    {
        int idx = b * TV + v;
        bool ok;
        if (flagF)      ok = (m[4 * idx + 3] != 0);  // float32 layout
        else if (flagB) ok = (m[idx] != 0);          // uint8/bool layout
        else            ok = (m[4 * idx] != 0);      // int32 LSB
        mk = ok ? __builtin_inff() : NEGV;
    }

    // ---- additive scores: s[r] = sum_u scale_u * tanh(q[r,u] + k[u,v]) ----
    const float* kb = kT + (size_t)b * UU * TV + v;
    float s0 = 0.f, s1 = 0.f, s2 = 0.f, s3 = 0.f;
    #pragma unroll 4
    for (int u = 0; u < UU; ++u) {
        float kv = kb[(size_t)u * TV];               // coalesced across v
        float w = sc[u];
        // tanh(x) = 1 - 2*rcp(1 + exp(2x)); saturates correctly at +-Inf
        float x0 = qs[u] + kv;
        float x1 = qs[UU + u] + kv;
        float x2 = qs[2 * UU + u] + kv;
        float x3 = qs[3 * UU + u] + kv;
        s0 = fmaf(w, 1.f - 2.f * fast_rcp(1.f + __expf(2.f * x0)), s0);
        s1 = fmaf(w, 1.f - 2.f * fast_rcp(1.f + __expf(2.f * x1)), s1);
        s2 = fmaf(w, 1.f - 2.f * fast_rcp(1.f + __expf(2.f * x2)), s2);
        s3 = fmaf(w, 1.f - 2.f * fast_rcp(1.f + __expf(2.f * x3)), s3);
    }
    float s[4] = { fminf(s0, mk), fminf(s1, mk), fminf(s2, mk), fminf(s3, mk) };

    // ---- masked softmax over v (256 threads = 4 wave64) ----
    int wid = v >> 6, lane = v & 63;
    float e[4];
    #pragma unroll
    for (int r = 0; r < 4; ++r) {
        float mm = s[r];
        #pragma unroll
        for (int off = 32; off >= 1; off >>= 1) mm = fmaxf(mm, __shfl_xor(mm, off));
        if (lane == 0) redM[r][wid] = mm;
    }
    __syncthreads();
    #pragma unroll
    for (int r = 0; r < 4; ++r) {
        float mfull = fmaxf(fmaxf(redM[r][0], redM[r][1]),
                            fmaxf(redM[r][2], redM[r][3]));
        e[r] = __expf(s[r] - mfull);
        float t = e[r];
        #pragma unroll
        for (int off = 32; off >= 1; off >>= 1) t += __shfl_xor(t, off);
        if (lane == 0) redS[r][wid] = t;
    }
    __syncthreads();
    #pragma unroll
    for (int r = 0; r < 4; ++r) {
        float rs = fast_rcp((redS[r][0] + redS[r][1]) + (redS[r][2] + redS[r][3]));
        float wv = e[r] * rs;
        wls[r * TV + v] = wv;
        weights[(size_t)(b * TQ + q0 + r) * TV + v] = wv;
    }
    __syncthreads();

    // ---- context: 4 rows x 512 d, each thread 2 d-columns ----
    const float* vb = value + (size_t)b * TV * DD + v;
    float c0=0.f,c1=0.f,c2=0.f,c3=0.f,c4=0.f,c5=0.f,c6=0.f,c7=0.f;
    #pragma unroll 4
    for (int t = 0; t < TV; ++t) {
        float va = vb[(size_t)t * DD];               // coalesced across v
        float vc = vb[(size_t)t * DD + 256];
        float w0 = wls[0 * TV + t], w1 = wls[1 * TV + t];
        float w2 = wls[2 * TV + t], w3 = wls[3 * TV + t];
        c0 = fmaf(w0, va, c0); c1 = fmaf(w1, va, c1);
        c2 = fmaf(w2, va, c2); c3 = fmaf(w3, va, c3);
        c4 = fmaf(w0, vc, c4); c5 = fmaf(w1, vc, c5);
        c6 = fmaf(w2, vc, c6); c7 = fmaf(w3, vc, c7);
    }
    float* op = ctx + (size_t)(b * TQ + q0) * DD + v;
    op[0 * DD]       = c0; op[1 * DD]       = c1;
    op[2 * DD]       = c2; op[3 * DD]       = c3;
    op[0 * DD + 256] = c4; op[1 * DD + 256] = c5;
    op[2 * DD + 256] = c6; op[3 * DD + 256] = c7;
}

extern "C" void kernel_launch(void* const* d_in, const int* in_sizes, int n_in,
                              void* d_out, int out_size, void* d_ws, size_t ws_size,
                              hipStream_t stream) {
    const float* query = (const float*)d_in[0];
    const float* value = (const float*)d_in[1];
    const unsigned char* mask = (const unsigned char*)d_in[2];
    const float* W1 = (const float*)d_in[3];
    const float* W2 = (const float*)d_in[4];
    const float* scale = (const float*)d_in[5];

    float* ctx = (float*)d_out;                              // [B,TQ,D]
    float* weights = (float*)d_out + (size_t)BB * TQ * DD;   // [B,TQ,TV]

    float* qp = (float*)d_ws;                                // 512 KB
    float* kT = qp + (size_t)BB * TQ * UU;                   // 512 KB

    proj_kernel<<<512, 256, 0, stream>>>(query, value, W1, W2, qp, kT);
    attn_kernel<<<256, 256, 0, stream>>>(qp, kT, scale, mask, value, ctx, weights);
}

// Round 4
// 38.328 us; speedup vs baseline: 1.9095x; 1.3105x over previous
//
#include <hip/hip_runtime.h>
#include <math.h>

#define BB 4
#define TQ 256
#define TV 256
#define DD 512
#define UU 128
#define NEGV (-1e9f)

__device__ __forceinline__ float fast_rcp(float x) {
    return __builtin_amdgcn_rcpf(x);   // v_rcp_f32, ~1 ulp
}

// ---------------- kernel 1: q & k projections -> Eq=exp(2q), Ek=exp(2k) ----------------
// grid 512 x 256 thr. blocks 0..255: q-proj (4 rows each); 256..511: k-proj.
// threads = 128 u-cols x 2 K-halves; halves combined through LDS.
__global__ __launch_bounds__(256) void proj_kernel(
    const float* __restrict__ query, const float* __restrict__ value,
    const float* __restrict__ W1, const float* __restrict__ W2,
    float* __restrict__ eqp /*[B*TQ][U] = exp(2q)*/,
    float* __restrict__ ekT /*[B][U][TV] = exp(2k)*/) {
    int bid = blockIdx.x;
    int which = bid >> 8;              // 0 = q, 1 = k
    int row0 = (bid & 255) * 4;
    const float* X = which ? value : query;
    const float* W = which ? W2 : W1;

    __shared__ float xs[4 * DD];       // 8 KB: 4 input rows
    __shared__ float cmb[4][UU];       // 2 KB: split-K partials
    int tid = threadIdx.x;
    for (int i = tid; i < 4 * DD / 4; i += 256)
        ((float4*)xs)[i] = ((const float4*)(X + (size_t)row0 * DD))[i];
    __syncthreads();

    int kc = tid >> 7;                 // K-half
    int u = tid & 127;
    const float* Wp = W + (size_t)(kc * (DD / 2)) * UU + u;
    const float* x0 = xs + kc * (DD / 2);
    float a0 = 0.f, a1 = 0.f, a2 = 0.f, a3 = 0.f;
    #pragma unroll 8
    for (int d = 0; d < DD / 2; ++d) {
        float w = Wp[(size_t)d * UU];          // coalesced across u
        a0 = fmaf(x0[d], w, a0);               // LDS broadcast
        a1 = fmaf(x0[DD + d], w, a1);
        a2 = fmaf(x0[2 * DD + d], w, a2);
        a3 = fmaf(x0[3 * DD + d], w, a3);
    }
    if (kc) { cmb[0][u] = a0; cmb[1][u] = a1; cmb[2][u] = a2; cmb[3][u] = a3; }
    __syncthreads();
    if (!kc) {
        a0 = __expf(2.f * (a0 + cmb[0][u]));
        a1 = __expf(2.f * (a1 + cmb[1][u]));
        a2 = __expf(2.f * (a2 + cmb[2][u]));
        a3 = __expf(2.f * (a3 + cmb[3][u]));
        if (which == 0) {
            float* p = eqp + (size_t)row0 * UU + u;
            p[0 * UU] = a0; p[1 * UU] = a1; p[2 * UU] = a2; p[3 * UU] = a3;
        } else {
            int b = row0 >> 8, v0 = row0 & 255;
            float* p = ekT + ((size_t)b * UU + u) * TV + v0;
            p[0] = a0; p[1] = a1; p[2] = a2; p[3] = a3;
        }
    }
}

// ---------------- kernel 2: scores + masked softmax -> weights ----------------
// grid 512 x 256 thr; each block owns 2 q-rows of one batch. 2 waves/SIMD.
__global__ __launch_bounds__(256) void scores_kernel(
    const float* __restrict__ eqp, const float* __restrict__ ekT,
    const float* __restrict__ scale, const unsigned char* __restrict__ m,
    float* __restrict__ weights) {
    int blk = blockIdx.x;              // 0..511
    int b = blk >> 7;
    int q0 = (blk & 127) * 2;
    int v = threadIdx.x;               // 0..255

    __shared__ float eq[2 * UU], sc[UU];
    __shared__ int flagF, flagB;
    __shared__ float redM[2][4], redS[2][4];
    if (v == 0) { flagF = 0; flagB = 0; }
    if (v < UU) sc[v] = scale[v];
    if (v < 2 * UU) eq[v] = eqp[(size_t)(b * TQ + q0) * UU + v];
    __syncthreads();

    // mask layout detection from the always-safe first 1024 bytes
    {
        uchar4 c4 = ((const uchar4*)m)[v];
        if (c4.w == 0x3f) flagF = 1;              // float32 1.0f high byte
        if (c4.y | c4.z | c4.w) flagB = 1;        // off-word nonzero -> u8
    }
    __syncthreads();
    float mk;
    {
        int idx = b * TV + v;
        bool ok;
        if (flagF)      ok = (m[4 * idx + 3] != 0);
        else if (flagB) ok = (m[idx] != 0);
        else            ok = (m[4 * idx] != 0);   // int32 LSB
        mk = ok ? __builtin_inff() : NEGV;
    }

    // s[r] = sum_u sc_u * (1 - 2/(1 + Eq[r,u]*Ek[u,v]))
    const float* kb = ekT + (size_t)b * UU * TV + v;
    float s0 = 0.f, s1 = 0.f;
    #pragma unroll 8
    for (int u = 0; u < UU; ++u) {
        float ek = kb[(size_t)u * TV];            // coalesced across v
        float w = sc[u];
        float r0 = fast_rcp(fmaf(eq[u], ek, 1.f));
        float r1 = fast_rcp(fmaf(eq[UU + u], ek, 1.f));
        s0 = fmaf(w, fmaf(-2.f, r0, 1.f), s0);
        s1 = fmaf(w, fmaf(-2.f, r1, 1.f), s1);
    }
    float s[2] = { fminf(s0, mk), fminf(s1, mk) };

    // masked softmax over v (4 wave64)
    int wid = v >> 6, lane = v & 63;
    float e[2];
    #pragma unroll
    for (int r = 0; r < 2; ++r) {
        float mm = s[r];
        #pragma unroll
        for (int off = 32; off >= 1; off >>= 1) mm = fmaxf(mm, __shfl_xor(mm, off));
        if (lane == 0) redM[r][wid] = mm;
    }
    __syncthreads();
    #pragma unroll
    for (int r = 0; r < 2; ++r) {
        float mfull = fmaxf(fmaxf(redM[r][0], redM[r][1]),
                            fmaxf(redM[r][2], redM[r][3]));
        e[r] = __expf(s[r] - mfull);
        float t = e[r];
        #pragma unroll
        for (int off = 32; off >= 1; off >>= 1) t += __shfl_xor(t, off);
        if (lane == 0) redS[r][wid] = t;
    }
    __syncthreads();
    #pragma unroll
    for (int r = 0; r < 2; ++r) {
        float rs = fast_rcp((redS[r][0] + redS[r][1]) + (redS[r][2] + redS[r][3]));
        weights[(size_t)(b * TQ + q0 + r) * TV + v] = e[r] * rs;
    }
}

// ---------------- kernel 3: context = weights @ value ----------------
// grid 512: 4 q-rows x 256-d half per block; 2 waves/SIMD.
__global__ __launch_bounds__(256) void context_kernel(
    const float* __restrict__ weights, const float* __restrict__ value,
    float* __restrict__ ctx) {
    int bid = blockIdx.x;              // 0..511
    int half = bid & 1;
    int grp = bid >> 1;                // 0..255
    int b = grp >> 6;
    int q0 = (grp & 63) * 4;
    int tid = threadIdx.x;             // 0..255
    __shared__ float w[4 * TV];        // 4 KB
    {
        const float* wsrc = weights + (size_t)(b * TQ + q0) * TV;
        for (int i = tid; i < 4 * TV; i += 256) w[i] = wsrc[i];
    }
    __syncthreads();
    const float* vb = value + (size_t)b * TV * DD + half * 256 + tid;
    float a0 = 0.f, a1 = 0.f, a2 = 0.f, a3 = 0.f;
    #pragma unroll 8
    for (int t = 0; t < TV; ++t) {
        float vv = vb[(size_t)t * DD];            // coalesced across tid
        a0 = fmaf(w[0 * TV + t], vv, a0);
        a1 = fmaf(w[1 * TV + t], vv, a1);
        a2 = fmaf(w[2 * TV + t], vv, a2);
        a3 = fmaf(w[3 * TV + t], vv, a3);
    }
    float* out = ctx + (size_t)(b * TQ + q0) * DD + half * 256 + tid;
    out[0 * DD] = a0; out[1 * DD] = a1; out[2 * DD] = a2; out[3 * DD] = a3;
}

extern "C" void kernel_launch(void* const* d_in, const int* in_sizes, int n_in,
                              void* d_out, int out_size, void* d_ws, size_t ws_size,
                              hipStream_t stream) {
    const float* query = (const float*)d_in[0];
    const float* value = (const float*)d_in[1];
    const unsigned char* mask = (const unsigned char*)d_in[2];
    const float* W1 = (const float*)d_in[3];
    const float* W2 = (const float*)d_in[4];
    const float* scale = (const float*)d_in[5];

    float* ctx = (float*)d_out;                              // [B,TQ,D]
    float* weights = (float*)d_out + (size_t)BB * TQ * DD;   // [B,TQ,TV]

    float* eqp = (float*)d_ws;                               // 512 KB
    float* ekT = eqp + (size_t)BB * TQ * UU;                 // 512 KB

    proj_kernel<<<512, 256, 0, stream>>>(query, value, W1, W2, eqp, ekT);
    scores_kernel<<<512, 256, 0, stream>>>(eqp, ekT, scale, mask, weights);
    context_kernel<<<512, 256, 0, stream>>>(weights, value, ctx);
}

// Round 5
// 34.162 us; speedup vs baseline: 2.1424x; 1.1220x over previous
//
#include <hip/hip_runtime.h>
#include <math.h>

#define BB 4
#define TQ 256
#define TV 256
#define DD 512
#define UU 128
#define NEGV (-1e9f)

__device__ __forceinline__ float fast_rcp(float x) {
    return __builtin_amdgcn_rcpf(x);   // v_rcp_f32
}

// ---------------- kernel 1: projections -> Eq=exp(2q) (paired), Ek=exp(2k) (transposed) ----------------
// 512 blocks x 512 thr. blocks 0..255: q-proj, 256..511: k-proj. 4 rows/block.
// threads = 128 u-cols x 4 K-quarters, combined via LDS. 4 waves/SIMD.
__global__ __launch_bounds__(512, 4) void proj_kernel(
    const float* __restrict__ query, const float* __restrict__ value,
    const float* __restrict__ W1, const float* __restrict__ W2,
    float* __restrict__ eqp /* [B*TQ/2][U][2] pairs of exp(2q) */,
    float* __restrict__ ekT /* [B][U][TV] = exp(2k) */) {
    int bid = blockIdx.x;
    int which = bid >> 8;              // 0 = q, 1 = k
    int row0 = (bid & 255) * 4;
    const float* X = which ? value : query;
    const float* W = which ? W2 : W1;

    __shared__ float xs[4 * DD];       // 8 KB: 4 input rows
    __shared__ float cmb[3][4][UU];    // 6 KB: split-K partials
    int tid = threadIdx.x;
    ((float4*)xs)[tid] = ((const float4*)(X + (size_t)row0 * DD))[tid];
    __syncthreads();

    int kc = tid >> 7;                 // K-quarter 0..3
    int u = tid & 127;
    const float* Wp = W + (size_t)(kc * (DD / 4)) * UU + u;
    const float* x0 = xs + kc * (DD / 4);
    float a0 = 0.f, a1 = 0.f, a2 = 0.f, a3 = 0.f;
    #pragma unroll 8
    for (int d = 0; d < DD / 4; ++d) {
        float w = Wp[(size_t)d * UU];          // coalesced across u
        a0 = fmaf(x0[d], w, a0);               // LDS broadcast
        a1 = fmaf(x0[DD + d], w, a1);
        a2 = fmaf(x0[2 * DD + d], w, a2);
        a3 = fmaf(x0[3 * DD + d], w, a3);
    }
    if (kc) {
        cmb[kc - 1][0][u] = a0; cmb[kc - 1][1][u] = a1;
        cmb[kc - 1][2][u] = a2; cmb[kc - 1][3][u] = a3;
    }
    __syncthreads();
    if (!kc) {
        a0 = __expf(2.f * (((a0 + cmb[0][0][u]) + cmb[1][0][u]) + cmb[2][0][u]));
        a1 = __expf(2.f * (((a1 + cmb[0][1][u]) + cmb[1][1][u]) + cmb[2][1][u]));
        a2 = __expf(2.f * (((a2 + cmb[0][2][u]) + cmb[1][2][u]) + cmb[2][2][u]));
        a3 = __expf(2.f * (((a3 + cmb[0][3][u]) + cmb[1][3][u]) + cmb[2][3][u]));
        if (which == 0) {
            int gp = row0 >> 1;                       // global row-pair index
            float2* p = (float2*)eqp;
            p[(size_t)gp * UU + u]       = make_float2(a0, a1);
            p[(size_t)(gp + 1) * UU + u] = make_float2(a2, a3);
        } else {
            int b = row0 >> 8, v0 = row0 & 255;
            float* p = ekT + ((size_t)b * UU + u) * TV + v0;
            p[0] = a0; p[1] = a1; p[2] = a2; p[3] = a3;
        }
    }
}

// ---------------- kernel 2: scores + masked softmax -> weights ----------------
// 512 blocks x 512 thr; block = 2 q-rows of one batch; thread = (v, u-half).
// s'[r,v] = -2 * sum_u sc_u * rcp(1 + Eq[r,u]*Ek[u,v])  (softmax shift-invariant:
// the +sum_u sc_u constant is common to all VALID entries; masked stay -1e9.)
__global__ __launch_bounds__(512, 4) void scores_kernel(
    const float* __restrict__ eqp, const float* __restrict__ ekT,
    const float* __restrict__ scale, const unsigned char* __restrict__ m,
    float* __restrict__ weights) {
    int blk = blockIdx.x;              // 0..511
    int b = blk >> 7;
    int gp = blk & 127;                // row pair within batch
    int tid = threadIdx.x;
    int v = tid & 255;
    int h = tid >> 8;                  // u-half

    __shared__ float2 eqL[UU];         // 1 KB
    __shared__ float sc2[UU];          // -2*scale
    __shared__ float pb[2][TV];        // 2 KB partial scores from h=1
    __shared__ int flagF, flagB;
    __shared__ float redM[2][4], redS[2][4];

    if (tid == 0) { flagF = 0; flagB = 0; }
    if (tid < UU) eqL[tid] = ((const float2*)eqp)[(size_t)(b * 128 + gp) * UU + tid];
    else if (tid < 2 * UU) sc2[tid - UU] = -2.f * scale[tid - UU];
    if (tid < 256) {                   // mask layout probe, first 1024 bytes safe
        uchar4 c4 = ((const uchar4*)m)[tid];
        if (c4.w == 0x3f) flagF = 1;                 // float32 1.0f high byte
        if (c4.y | c4.z | c4.w) flagB = 1;           // off-word nonzero -> u8
    }
    __syncthreads();

    const float* kb = ekT + ((size_t)b * UU + h * 64) * TV + v;
    float s0 = 0.f, s1 = 0.f;
    #pragma unroll 8
    for (int i = 0; i < 64; ++i) {
        float ek = kb[(size_t)i * TV];               // coalesced across v
        float2 eq2 = eqL[h * 64 + i];                // LDS broadcast
        float w2 = sc2[h * 64 + i];
        float r0 = fast_rcp(fmaf(eq2.x, ek, 1.f));
        float r1 = fast_rcp(fmaf(eq2.y, ek, 1.f));
        s0 = fmaf(w2, r0, s0);
        s1 = fmaf(w2, r1, s1);
    }
    if (h == 1) { pb[0][v] = s0; pb[1][v] = s1; }
    __syncthreads();

    float mk;
    {
        int idx = b * TV + v;
        bool ok;
        if (flagF)      ok = (m[4 * idx + 3] != 0);
        else if (flagB) ok = (m[idx] != 0);
        else            ok = (m[4 * idx] != 0);      // int32 LSB
        mk = ok ? __builtin_inff() : NEGV;
    }
    float s[2];
    s[0] = fminf(s0 + pb[0][v], mk);                 // h=1 lanes: garbage, unused
    s[1] = fminf(s1 + pb[1][v], mk);

    int wid = tid >> 6, lane = tid & 63;
    float e[2];
    #pragma unroll
    for (int r = 0; r < 2; ++r) {
        float mm = s[r];
        #pragma unroll
        for (int off = 32; off >= 1; off >>= 1) mm = fmaxf(mm, __shfl_xor(mm, off));
        if (h == 0 && lane == 0) redM[r][wid] = mm;
    }
    __syncthreads();
    #pragma unroll
    for (int r = 0; r < 2; ++r) {
        float mfull = fmaxf(fmaxf(redM[r][0], redM[r][1]),
                            fmaxf(redM[r][2], redM[r][3]));
        e[r] = __expf(s[r] - mfull);
        float t = e[r];
        #pragma unroll
        for (int off = 32; off >= 1; off >>= 1) t += __shfl_xor(t, off);
        if (h == 0 && lane == 0) redS[r][wid] = t;
    }
    __syncthreads();
    if (h == 0) {
        #pragma unroll
        for (int r = 0; r < 2; ++r) {
            float rs = fast_rcp((redS[r][0] + redS[r][1]) + (redS[r][2] + redS[r][3]));
            weights[(size_t)(b * TQ + gp * 2 + r) * TV + v] = e[r] * rs;
        }
    }
}

// ---------------- kernel 3: context partials, v-split-2 ----------------
// 512 blocks x 512 thr: (b, 4 q-rows, v-half). thread = one d column.
__global__ __launch_bounds__(512, 4) void context_kernel(
    const float* __restrict__ weights, const float* __restrict__ value,
    float* __restrict__ ctx, float* __restrict__ part) {
    int bid = blockIdx.x;
    int vh = bid & 1;
    int grp = bid >> 1;
    int b = grp >> 6;
    int q0 = (grp & 63) * 4;
    int tid = threadIdx.x;             // d column
    __shared__ float w[4][128];        // 2 KB
    if (tid < 512) {
        int r = tid >> 7, j = tid & 127;
        w[r][j] = weights[(size_t)(b * TQ + q0 + r) * TV + vh * 128 + j];
    }
    __syncthreads();
    const float* vb = value + ((size_t)b * TV + vh * 128) * DD + tid;
    float a0 = 0.f, a1 = 0.f, a2 = 0.f, a3 = 0.f;
    #pragma unroll 8
    for (int t = 0; t < 128; ++t) {
        float vv = vb[(size_t)t * DD];               // coalesced across tid
        a0 = fmaf(w[0][t], vv, a0);
        a1 = fmaf(w[1][t], vv, a1);
        a2 = fmaf(w[2][t], vv, a2);
        a3 = fmaf(w[3][t], vv, a3);
    }
    float* out = (vh ? part : ctx) + (size_t)(b * TQ + q0) * DD + tid;
    out[0 * DD] = a0; out[1 * DD] = a1; out[2 * DD] = a2; out[3 * DD] = a3;
}

// ---------------- kernel 3-fallback: full-v context (if ws too small) ----------------
__global__ __launch_bounds__(256) void context_kernel_ns(
    const float* __restrict__ weights, const float* __restrict__ value,
    float* __restrict__ ctx) {
    int bid = blockIdx.x;              // 0..511
    int half = bid & 1;
    int grp = bid >> 1;
    int b = grp >> 6;
    int q0 = (grp & 63) * 4;
    int tid = threadIdx.x;
    __shared__ float w[4 * TV];
    {
        const float* wsrc = weights + (size_t)(b * TQ + q0) * TV;
        for (int i = tid; i < 4 * TV; i += 256) w[i] = wsrc[i];
    }
    __syncthreads();
    const float* vb = value + (size_t)b * TV * DD + half * 256 + tid;
    float a0 = 0.f, a1 = 0.f, a2 = 0.f, a3 = 0.f;
    #pragma unroll 8
    for (int t = 0; t < TV; ++t) {
        float vv = vb[(size_t)t * DD];
        a0 = fmaf(w[0 * TV + t], vv, a0);
        a1 = fmaf(w[1 * TV + t], vv, a1);
        a2 = fmaf(w[2 * TV + t], vv, a2);
        a3 = fmaf(w[3 * TV + t], vv, a3);
    }
    float* out = ctx + (size_t)(b * TQ + q0) * DD + half * 256 + tid;
    out[0 * DD] = a0; out[1 * DD] = a1; out[2 * DD] = a2; out[3 * DD] = a3;
}

// ---------------- kernel 4: ctx += part (float4) ----------------
__global__ __launch_bounds__(256) void ctx_reduce_kernel(
    float* __restrict__ ctx, const float* __restrict__ part) {
    size_t i = (size_t)blockIdx.x * 256 + threadIdx.x;   // 131072 float4
    float4 a = ((const float4*)ctx)[i];
    float4 b = ((const float4*)part)[i];
    a.x += b.x; a.y += b.y; a.z += b.z; a.w += b.w;
    ((float4*)ctx)[i] = a;
}

extern "C" void kernel_launch(void* const* d_in, const int* in_sizes, int n_in,
                              void* d_out, int out_size, void* d_ws, size_t ws_size,
                              hipStream_t stream) {
    const float* query = (const float*)d_in[0];
    const float* value = (const float*)d_in[1];
    const unsigned char* mask = (const unsigned char*)d_in[2];
    const float* W1 = (const float*)d_in[3];
    const float* W2 = (const float*)d_in[4];
    const float* scale = (const float*)d_in[5];

    float* ctx = (float*)d_out;                              // [B,TQ,D]
    float* weights = (float*)d_out + (size_t)BB * TQ * DD;   // [B,TQ,TV]

    float* eqp = (float*)d_ws;                               // 512 KB (pairs)
    float* ekT = eqp + (size_t)BB * TQ * UU;                 // 512 KB
    float* part = ekT + (size_t)BB * UU * TV;                // 2 MB (ctx partials)
    size_t need = ((size_t)BB * TQ * UU * 2 + (size_t)BB * TQ * DD) * sizeof(float);

    proj_kernel<<<512, 512, 0, stream>>>(query, value, W1, W2, eqp, ekT);
    scores_kernel<<<512, 512, 0, stream>>>(eqp, ekT, scale, mask, weights);
    if (ws_size >= need) {
        context_kernel<<<512, 512, 0, stream>>>(weights, value, ctx, part);
        ctx_reduce_kernel<<<512, 256, 0, stream>>>(ctx, part);
    } else {
        context_kernel_ns<<<512, 256, 0, stream>>>(weights, value, ctx);
    }
}